// Round 1
// baseline (700.902 us; speedup 1.0000x reference)
//
#include <hip/hip_runtime.h>
#include <math.h>

// DotAttention: context[b,f] = sum_t softmax_t(<hd[b],he[b,t]>) * he[b,t,f]
// One-pass flash-style: he (512 MiB, > L3) is read exactly once.

#define BB 64
#define TT 2048
#define FF 1024

// Pass 1: each block handles (batch b, t-chunk s). 4 waves/block, each wave
// streams its share of t's, keeping online-softmax state (m, l) and a full
// 1024-wide context partial in registers (lane holds f = 4*lane + 256*r).
__global__ __launch_bounds__(256) void attn_pass1(
    const float* __restrict__ hd, const float* __restrict__ he,
    float* __restrict__ part_ctx, float* __restrict__ part_m,
    float* __restrict__ part_l, int S, int Tc)
{
    const int bid  = blockIdx.x;
    const int b    = bid / S;
    const int s    = bid - b * S;
    const int t0   = s * Tc;
    const int lane = threadIdx.x & 63;
    const int wave = threadIdx.x >> 6;

    // hd[b] resident in registers, same f-layout as the accumulator
    const float* hdb = hd + (size_t)b * FF;
    float4 hdv[4];
#pragma unroll
    for (int r = 0; r < 4; ++r)
        hdv[r] = *(const float4*)(hdb + 4 * lane + 256 * r);

    float m = -INFINITY, l = 0.f;
    float4 ctx[4];
#pragma unroll
    for (int r = 0; r < 4; ++r) ctx[r] = make_float4(0.f, 0.f, 0.f, 0.f);

    const float* heb = he + ((size_t)b * TT + t0) * (size_t)FF;

    for (int i = wave; i < Tc; i += 4) {
        const float* het = heb + (size_t)i * FF;
        float4 hev[4];
#pragma unroll
        for (int r = 0; r < 4; ++r)
            hev[r] = *(const float4*)(het + 4 * lane + 256 * r);

        // dot(hd[b], he[b,t]) : per-lane partial then 64-lane butterfly
        float d = 0.f;
#pragma unroll
        for (int r = 0; r < 4; ++r) {
            d += hdv[r].x * hev[r].x + hdv[r].y * hev[r].y +
                 hdv[r].z * hev[r].z + hdv[r].w * hev[r].w;
        }
#pragma unroll
        for (int off = 32; off >= 1; off >>= 1)
            d += __shfl_xor(d, off, 64);

        // online softmax update
        const float mn    = fmaxf(m, d);
        const float alpha = __expf(m - mn);   // exp(-inf)=0 on first iter
        const float w     = __expf(d - mn);
#pragma unroll
        for (int r = 0; r < 4; ++r) {
            ctx[r].x = ctx[r].x * alpha + w * hev[r].x;
            ctx[r].y = ctx[r].y * alpha + w * hev[r].y;
            ctx[r].z = ctx[r].z * alpha + w * hev[r].z;
            ctx[r].w = ctx[r].w * alpha + w * hev[r].w;
        }
        l = l * alpha + w;
        m = mn;
    }

    // combine the 4 waves' partials through LDS
    __shared__ float sm_ctx[4][FF];
    __shared__ float sm_m[4], sm_l[4];
#pragma unroll
    for (int r = 0; r < 4; ++r)
        *(float4*)&sm_ctx[wave][4 * lane + 256 * r] = ctx[r];
    if (lane == 0) { sm_m[wave] = m; sm_l[wave] = l; }
    __syncthreads();

    const float M  = fmaxf(fmaxf(sm_m[0], sm_m[1]), fmaxf(sm_m[2], sm_m[3]));
    const float e0 = __expf(sm_m[0] - M);
    const float e1 = __expf(sm_m[1] - M);
    const float e2 = __expf(sm_m[2] - M);
    const float e3 = __expf(sm_m[3] - M);

    const int f4 = threadIdx.x * 4;
    const float4 c0 = *(const float4*)&sm_ctx[0][f4];
    const float4 c1 = *(const float4*)&sm_ctx[1][f4];
    const float4 c2 = *(const float4*)&sm_ctx[2][f4];
    const float4 c3 = *(const float4*)&sm_ctx[3][f4];
    float4 o;
    o.x = e0 * c0.x + e1 * c1.x + e2 * c2.x + e3 * c3.x;
    o.y = e0 * c0.y + e1 * c1.y + e2 * c2.y + e3 * c3.y;
    o.z = e0 * c0.z + e1 * c1.z + e2 * c2.z + e3 * c3.z;
    o.w = e0 * c0.w + e1 * c1.w + e2 * c2.w + e3 * c3.w;
    *(float4*)(part_ctx + (size_t)bid * FF + f4) = o;

    if (threadIdx.x == 0) {
        part_m[bid] = M;
        part_l[bid] = e0 * sm_l[0] + e1 * sm_l[1] + e2 * sm_l[2] + e3 * sm_l[3];
    }
}

// Pass 2: per batch, combine S chunk-partials and normalize.
__global__ __launch_bounds__(256) void attn_pass2(
    const float* __restrict__ part_ctx, const float* __restrict__ part_m,
    const float* __restrict__ part_l, float* __restrict__ out, int S)
{
    const int b = blockIdx.x;

    float M = -INFINITY;
    for (int s = 0; s < S; ++s) M = fmaxf(M, part_m[b * S + s]);
    float L = 0.f;
    for (int s = 0; s < S; ++s)
        L += part_l[b * S + s] * __expf(part_m[b * S + s] - M);

    const int f4 = threadIdx.x * 4;
    float4 acc = make_float4(0.f, 0.f, 0.f, 0.f);
    for (int s = 0; s < S; ++s) {
        const float e  = __expf(part_m[b * S + s] - M);
        const float4 c = *(const float4*)(part_ctx + ((size_t)(b * S + s)) * FF + f4);
        acc.x += e * c.x; acc.y += e * c.y; acc.z += e * c.z; acc.w += e * c.w;
    }
    const float inv = 1.f / L;
    float4 o = make_float4(acc.x * inv, acc.y * inv, acc.z * inv, acc.w * inv);
    *(float4*)(out + (size_t)b * FF + f4) = o;
}

extern "C" void kernel_launch(void* const* d_in, const int* in_sizes, int n_in,
                              void* d_out, int out_size, void* d_ws, size_t ws_size,
                              hipStream_t stream) {
    const float* hd = (const float*)d_in[0];   // (64, 1024) f32
    const float* he = (const float*)d_in[1];   // (64, 2048, 1024) f32
    float* out = (float*)d_out;                // (64, 1024) f32

    // pick largest split count whose partials fit in the workspace
    int S = 32;
    while (S > 1 && (size_t)BB * S * (FF * sizeof(float) + 2 * sizeof(float)) > ws_size)
        S >>= 1;
    const int Tc = TT / S;

    float* part_ctx = (float*)d_ws;                      // B*S*F
    float* part_m   = part_ctx + (size_t)BB * S * FF;    // B*S
    float* part_l   = part_m + (size_t)BB * S;           // B*S

    attn_pass1<<<BB * S, 256, 0, stream>>>(hd, he, part_ctx, part_m, part_l, S, Tc);
    attn_pass2<<<BB, 256, 0, stream>>>(part_ctx, part_m, part_l, out, S);
}

// Round 2
// 698.352 us; speedup vs baseline: 1.0037x; 1.0037x over previous
//
#include <hip/hip_runtime.h>
#include <math.h>

// DotAttention: context[b,f] = sum_t softmax_t(<hd[b],he[b,t]>) * he[b,t,f]
// One-pass flash-style, block-level online softmax.
// he (512 MiB > L3) is streamed exactly once via async global->LDS staging.

#define BB 64
#define TT 2048
#define FF 1024
#define RR 4          // rows per tile (4 KiB each -> 16 KiB tile, double-buffered)

typedef __attribute__((address_space(1))) const void* gas_ptr;
typedef __attribute__((address_space(3))) void* las_ptr;

// async 16B-per-lane global->LDS: LDS dest = uniform base + lane*16
__device__ __forceinline__ void gld_lds16(const float* g, float* l) {
    __builtin_amdgcn_global_load_lds((gas_ptr)g, (las_ptr)l, 16, 0, 0);
}

// Pass 1: block handles (batch b, t-chunk s). Tiles of RR rows staged to LDS
// (double-buffered, async). All 4 waves redundantly compute the RR row-dots
// (independent butterflies), then the block-wide online-softmax update runs
// once per tile; each thread owns a 4-float f-slice of the context.
__global__ __launch_bounds__(256) void attn_pass1(
    const float* __restrict__ hd, const float* __restrict__ he,
    float* __restrict__ part_ctx, float* __restrict__ part_m,
    float* __restrict__ part_l, int S, int Tc)
{
    const int bid  = blockIdx.x;
    const int b    = bid / S;
    const int s    = bid - b * S;
    const int t0   = s * Tc;
    const int lane = threadIdx.x & 63;
    const int wave = threadIdx.x >> 6;
    const int nt   = Tc / RR;

    __shared__ float buf[2][RR * FF];   // 2 x 16 KiB

    // hd[b] fragment matching the dot read layout: elements 4*lane + 256*k
    const float* hdb = hd + (size_t)b * FF;
    float4 hdv[4];
#pragma unroll
    for (int k = 0; k < 4; ++k)
        hdv[k] = *(const float4*)(hdb + 4 * lane + 256 * k);

    const float* heb = he + ((size_t)b * TT + t0) * (size_t)FF;

    float m = -INFINITY, l = 0.f;
    float4 ctx = make_float4(0.f, 0.f, 0.f, 0.f);

    // prologue: stage tile 0 into buf[0] (wave w stages row w, 4 x 1 KiB)
    {
        const float* row = heb + (size_t)wave * FF;
#pragma unroll
        for (int k = 0; k < 4; ++k)
            gld_lds16(row + k * 256 + lane * 4, &buf[0][wave * FF + k * 256]);
    }

    for (int kt = 0; kt < nt; ++kt) {
        const int cur = kt & 1;
        __syncthreads();   // drains vmcnt: tile kt staged; buf[cur^1] is dead

        // stage tile kt+1 into the dead buffer — overlaps the whole compute phase
        if (kt + 1 < nt) {
            const float* row = heb + ((size_t)(kt + 1) * RR + wave) * FF;
#pragma unroll
            for (int k = 0; k < 4; ++k)
                gld_lds16(row + k * 256 + lane * 4,
                          &buf[cur ^ 1][wave * FF + k * 256]);
        }

        // all RR row-dots, redundantly per wave (no score-sharing barrier)
        float d[RR];
#pragma unroll
        for (int r = 0; r < RR; ++r) {
            float4 hv[4];
#pragma unroll
            for (int k = 0; k < 4; ++k)
                hv[k] = *(const float4*)&buf[cur][r * FF + 4 * lane + 256 * k];
            float acc = 0.f;
#pragma unroll
            for (int k = 0; k < 4; ++k)
                acc += hdv[k].x * hv[k].x + hdv[k].y * hv[k].y +
                       hdv[k].z * hv[k].z + hdv[k].w * hv[k].w;
            d[r] = acc;
        }
        // 4 independent butterflies, interleaved for DS-latency ILP
#pragma unroll
        for (int off = 32; off >= 1; off >>= 1) {
#pragma unroll
            for (int r = 0; r < RR; ++r)
                d[r] += __shfl_xor(d[r], off, 64);
        }

        // block-wide online softmax update (identical in every thread)
        float mn = m;
#pragma unroll
        for (int r = 0; r < RR; ++r) mn = fmaxf(mn, d[r]);
        const float alpha = __expf(m - mn);   // exp(-inf)=0 on first tile
        float w[RR], wsum = 0.f;
#pragma unroll
        for (int r = 0; r < RR; ++r) { w[r] = __expf(d[r] - mn); wsum += w[r]; }

        // accumulate this thread's 4-float f-slice
        const int f4 = threadIdx.x * 4;
        float4 a = make_float4(ctx.x * alpha, ctx.y * alpha,
                               ctx.z * alpha, ctx.w * alpha);
#pragma unroll
        for (int r = 0; r < RR; ++r) {
            const float4 rv = *(const float4*)&buf[cur][r * FF + f4];
            a.x += w[r] * rv.x; a.y += w[r] * rv.y;
            a.z += w[r] * rv.z; a.w += w[r] * rv.w;
        }
        ctx = a;
        l = l * alpha + wsum;
        m = mn;
    }

    // per-thread slice is the block's partial — no cross-wave combine needed
    *(float4*)(part_ctx + (size_t)bid * FF + threadIdx.x * 4) = ctx;
    if (threadIdx.x == 0) { part_m[bid] = m; part_l[bid] = l; }
}

// Pass 2: per batch, combine S chunk-partials and normalize.
__global__ __launch_bounds__(256) void attn_pass2(
    const float* __restrict__ part_ctx, const float* __restrict__ part_m,
    const float* __restrict__ part_l, float* __restrict__ out, int S)
{
    const int b = blockIdx.x;

    float M = -INFINITY;
    for (int s = 0; s < S; ++s) M = fmaxf(M, part_m[b * S + s]);
    float L = 0.f;
    for (int s = 0; s < S; ++s)
        L += part_l[b * S + s] * __expf(part_m[b * S + s] - M);

    const int f4 = threadIdx.x * 4;
    float4 acc = make_float4(0.f, 0.f, 0.f, 0.f);
    for (int s = 0; s < S; ++s) {
        const float e  = __expf(part_m[b * S + s] - M);
        const float4 c = *(const float4*)(part_ctx + ((size_t)(b * S + s)) * FF + f4);
        acc.x += e * c.x; acc.y += e * c.y; acc.z += e * c.z; acc.w += e * c.w;
    }
    const float inv = 1.f / L;
    float4 o = make_float4(acc.x * inv, acc.y * inv, acc.z * inv, acc.w * inv);
    *(float4*)(out + (size_t)b * FF + f4) = o;
}

extern "C" void kernel_launch(void* const* d_in, const int* in_sizes, int n_in,
                              void* d_out, int out_size, void* d_ws, size_t ws_size,
                              hipStream_t stream) {
    const float* hd = (const float*)d_in[0];   // (64, 1024) f32
    const float* he = (const float*)d_in[1];   // (64, 2048, 1024) f32
    float* out = (float*)d_out;                // (64, 1024) f32

    // largest split count whose partials fit in the workspace
    int S = 32;
    while (S > 1 && (size_t)BB * S * (FF * sizeof(float) + 2 * sizeof(float)) > ws_size)
        S >>= 1;
    const int Tc = TT / S;   // 64 at S=32 -> 16 tiles of RR=4

    float* part_ctx = (float*)d_ws;                      // B*S*F
    float* part_m   = part_ctx + (size_t)BB * S * FF;    // B*S
    float* part_l   = part_m + (size_t)BB * S;           // B*S

    attn_pass1<<<BB * S, 256, 0, stream>>>(hd, he, part_ctx, part_m, part_l, S, Tc);
    attn_pass2<<<BB, 256, 0, stream>>>(part_ctx, part_m, part_l, out, S);
}